// Round 13
// baseline (445.341 us; speedup 1.0000x reference)
//
#include <hip/hip_runtime.h>
#include <hip/hip_bf16.h>

#define NN 50000
#define NE 800000
#define FIN 128
#define HC 256
#define NEG_SLOPE 0.2f

#define GEMM_BLOCKS 1564  // ceil(NN/64)*2  (64x128 tiles)
#define NSB 3321          // ceil((NE+NN)/256) scatter blocks
#define NB_ZERO 196       // ceil(NN/256)
#define NB_X 6250         // NN*FIN/4/256
#define NB_W1 128         // FIN*HC/256
#define NB_W2 256         // HC*HC/256

typedef short bf16x8 __attribute__((ext_vector_type(8)));
typedef float f32x4 __attribute__((ext_vector_type(4)));

__device__ __forceinline__ unsigned short f2bf(float f) {
  unsigned u = __float_as_uint(f);
  u += 0x7fff + ((u >> 16) & 1);  // RTN-even
  return (unsigned short)(u >> 16);
}
__device__ __forceinline__ float bf2f(unsigned short s) {
  return __uint_as_float((unsigned)s << 16);
}
__device__ __forceinline__ float bflo(unsigned u) { return __uint_as_float(u << 16); }
__device__ __forceinline__ float bfhi(unsigned u) { return __uint_as_float(u & 0xffff0000u); }

// ---------------- fused prep: zero counts/tmp + convert x + transpose/split W1,W2 ----
__global__ __launch_bounds__(256) void prep_kernel(
    const float* __restrict__ X, unsigned short* __restrict__ Xh,
    const float* __restrict__ W1, unsigned short* __restrict__ W1th,
    unsigned short* __restrict__ W1tl, const float* __restrict__ W2,
    unsigned short* __restrict__ W2th, unsigned short* __restrict__ W2tl,
    int* __restrict__ counts, int* __restrict__ tmp) {
  int b = blockIdx.x, t = threadIdx.x;
  if (b < NB_ZERO) {
    int i = b * 256 + t;
    if (i < NN) { counts[i] = 0; tmp[i] = 0; }
  } else if (b < NB_ZERO + NB_X) {
    int i = (b - NB_ZERO) * 256 + t;  // exact: NN*FIN/4 = 1.6M
    float4 v = ((const float4*)X)[i];
    ushort4 h;
    h.x = f2bf(v.x); h.y = f2bf(v.y); h.z = f2bf(v.z); h.w = f2bf(v.w);
    ((ushort4*)Xh)[i] = h;
  } else if (b < NB_ZERO + NB_X + NB_W1) {
    int j = (b - NB_ZERO - NB_X) * 256 + t;  // j = n*K+k, output-contiguous, K=128
    int n = j >> 7, k = j & 127;
    float v = W1[k * HC + n];
    unsigned short h = f2bf(v);
    W1th[j] = h;
    W1tl[j] = f2bf(v - bf2f(h));
  } else {
    int j = (b - NB_ZERO - NB_X - NB_W1) * 256 + t;  // K=256
    int n = j >> 8, k = j & 255;
    float v = W2[k * HC + n];
    unsigned short h = f2bf(v);
    W2th[j] = h;
    W2tl[j] = f2bf(v - bf2f(h));
  }
}

// ---------------- MFMA GEMM + fused coef, 64x128 tile, reg-prefetch dbuf ----------
// Cb(bf16) = A_bf16 @ (Bh+Bl)^T(stored [N][K]); 2-term split.
// K-loop: next tile's 5 uint4 global loads issued after barrier-2 and consumed at
// the next loop top, so global latency overlaps the MFMA section (round-12's
// load->barrier->use chain left MfmaUtil at 3% — latency-bound, not BW).
// Coef: 16-lane shuffle reduce -> LDS -> one float4/row (contiguous; scattered 4B
// coef stores amplified WRITE to 85MB in r11). C stored as quad-contiguous 2B
// scalars (r10's strided uint4 stores amplified writes 3x — do not repeat).
// Scatter blocks come FIRST in the layer-1 grid so they complete under the gemm.
__global__ __launch_bounds__(256) void gemm_coef(
    const unsigned short* __restrict__ A, const unsigned short* __restrict__ Bth,
    const unsigned short* __restrict__ Btl, const float* __restrict__ att_s,
    const float* __restrict__ att_d, unsigned short* __restrict__ Cb,
    float* __restrict__ a_s, float* __restrict__ a_d, int M, int K,
    const int* __restrict__ ei, const int* __restrict__ rowptr,
    int* __restrict__ tmpc, int2* __restrict__ ce, int scat) {
  __shared__ unsigned short sA[64 * 40];    // stride 40 shorts: <=2-way banks (free)
  __shared__ unsigned short sBh[128 * 40];
  __shared__ unsigned short sBl[128 * 40];
  __shared__ float sCS[64][4];
  __shared__ float sCD[64][4];

  int bid = blockIdx.x, t = threadIdx.x;
  if (bid < scat) {
    // fused scatter path (layer-1 launch only), dispatched before gemm blocks
    int e = bid * 256 + t;
    if (e < NE + NN) {
      int s, d, id;
      if (e < NE) { s = ei[e]; d = ei[NE + e]; id = e; }
      else { s = d = e - NE; id = -1; }
      int pos = rowptr[d] + atomicAdd(&tmpc[d], 1);
      ce[pos] = make_int2(s, id);
    }
    return;
  }
  int gid = bid - scat;

  int w = t >> 6, lane = t & 63;
  int quad = lane >> 4, lrow = lane & 15;
  int m0 = (gid >> 1) * 64, n0 = (gid & 1) * 128;
  int rm = (w & 1) * 32, cn = (w >> 1) * 64;

  // staging coordinates (fixed per thread)
  int rowA = t >> 2, qA = t & 3;                 // A: 64 rows x 4 chunks
  int gmA = m0 + rowA; if (gmA >= M) gmA = M - 1;
  const unsigned short* pA = A + (size_t)gmA * K + qA * 8;
  int rowB0 = t >> 2;                            // B chunk 1: rows 0..63
  int rowB1 = (t + 256) >> 2;                    // B chunk 2: rows 64..127
  const unsigned short* pBh0 = Bth + (size_t)(n0 + rowB0) * K + qA * 8;
  const unsigned short* pBh1 = Bth + (size_t)(n0 + rowB1) * K + qA * 8;
  const unsigned short* pBl0 = Btl + (size_t)(n0 + rowB0) * K + qA * 8;
  const unsigned short* pBl1 = Btl + (size_t)(n0 + rowB1) * K + qA * 8;

  // prologue: load tile 0 into registers
  uint4 ra  = *(const uint4*)(pA);
  uint4 rh0 = *(const uint4*)(pBh0);
  uint4 rh1 = *(const uint4*)(pBh1);
  uint4 rl0 = *(const uint4*)(pBl0);
  uint4 rl1 = *(const uint4*)(pBl1);

  f32x4 acc[2][4] = {};

  for (int k0 = 0; k0 < K; k0 += 32) {
    __syncthreads();  // previous iteration's LDS readers done
    *(uint4*)(sA + rowA * 40 + qA * 8) = ra;
    *(uint4*)(sBh + rowB0 * 40 + qA * 8) = rh0;
    *(uint4*)(sBh + rowB1 * 40 + qA * 8) = rh1;
    *(uint4*)(sBl + rowB0 * 40 + qA * 8) = rl0;
    *(uint4*)(sBl + rowB1 * 40 + qA * 8) = rl1;
    __syncthreads();

    int k1 = k0 + 32;
    if (k1 < K) {  // prefetch next tile; latency hidden by the MFMA section below
      ra  = *(const uint4*)(pA + k1);
      rh0 = *(const uint4*)(pBh0 + k1);
      rh1 = *(const uint4*)(pBh1 + k1);
      rl0 = *(const uint4*)(pBl0 + k1);
      rl1 = *(const uint4*)(pBl1 + k1);
    }

    bf16x8 fa[2];
#pragma unroll
    for (int mi = 0; mi < 2; ++mi)
      fa[mi] = *(const bf16x8*)(sA + (rm + mi * 16 + lrow) * 40 + quad * 8);
#pragma unroll
    for (int ni = 0; ni < 4; ++ni) {
      bf16x8 fbh = *(const bf16x8*)(sBh + (cn + ni * 16 + lrow) * 40 + quad * 8);
      bf16x8 fbl = *(const bf16x8*)(sBl + (cn + ni * 16 + lrow) * 40 + quad * 8);
#pragma unroll
      for (int mi = 0; mi < 2; ++mi) {
        acc[mi][ni] = __builtin_amdgcn_mfma_f32_16x16x32_bf16(fa[mi], fbh, acc[mi][ni], 0, 0, 0);
        acc[mi][ni] = __builtin_amdgcn_mfma_f32_16x16x32_bf16(fa[mi], fbl, acc[mi][ni], 0, 0, 0);
      }
    }
  }

  // att values for this lane's 4 columns (hoisted)
  float vs[4], vd[4];
#pragma unroll
  for (int ni = 0; ni < 4; ++ni) {
    int gn = n0 + cn + ni * 16 + lrow;
    vs[ni] = att_s[gn];
    vd[ni] = att_d[gn];
  }
  int h4e = cn >> 5;  // local head pair base: 0 (cols 0-63) or 2 (cols 64-127)

  // C/D layout: col = lane&15, row = quad*4 + reg  [m89-verified]
#pragma unroll
  for (int mi = 0; mi < 2; ++mi) {
#pragma unroll
    for (int r = 0; r < 4; ++r) {
      int lr = rm + mi * 16 + quad * 4 + r;  // local row 0..63
      int gm = m0 + lr;
      if (gm < M) {
#pragma unroll
        for (int ni = 0; ni < 4; ++ni) {
          int gn = n0 + cn + ni * 16 + lrow;
          Cb[(size_t)gm * HC + gn] = f2bf(acc[mi][ni][r]);
        }
      }
      // per-head partial dots: ni 0,1 -> local head h4e ; ni 2,3 -> h4e+1
      float pse = acc[mi][0][r] * vs[0] + acc[mi][1][r] * vs[1];
      float pso = acc[mi][2][r] * vs[2] + acc[mi][3][r] * vs[3];
      float pde = acc[mi][0][r] * vd[0] + acc[mi][1][r] * vd[1];
      float pdo = acc[mi][2][r] * vd[2] + acc[mi][3][r] * vd[3];
#pragma unroll
      for (int off = 1; off <= 8; off <<= 1) {
        pse += __shfl_xor(pse, off);
        pso += __shfl_xor(pso, off);
        pde += __shfl_xor(pde, off);
        pdo += __shfl_xor(pdo, off);
      }
      if (lrow == 0) {
        sCS[lr][h4e] = pse;
        sCS[lr][h4e + 1] = pso;
        sCD[lr][h4e] = pde;
        sCD[lr][h4e + 1] = pdo;
      }
    }
  }
  __syncthreads();
  // contiguous 16B coef writeback (one float4 per row per array)
  if (t < 64) {
    int gm = m0 + t;
    if (gm < M) {
      int o = (n0 >> 5);  // 0 or 4
      *(float4*)(a_s + (size_t)gm * 8 + o) = *(const float4*)&sCS[t][0];
      *(float4*)(a_d + (size_t)gm * 8 + o) = *(const float4*)&sCD[t][0];
    }
  }
}

// ---------------- CSR build ----------------
__global__ void hist_kernel(const int* __restrict__ ei, int* __restrict__ counts) {
  int e = blockIdx.x * 256 + threadIdx.x;
  if (e < NE) atomicAdd(&counts[ei[NE + e]], 1);
}

__global__ void scan1(const int* __restrict__ counts, int* __restrict__ scanbuf,
                      int* __restrict__ bsum) {
  __shared__ int sd[256];
  int t = threadIdx.x;
  int i = blockIdx.x * 256 + t;
  int v = (i < NN) ? counts[i] + 1 : 0;  // +1 = self-loop
  sd[t] = v;
  __syncthreads();
#pragma unroll
  for (int off = 1; off < 256; off <<= 1) {
    int x = (t >= off) ? sd[t - off] : 0;
    __syncthreads();
    sd[t] += x;
    __syncthreads();
  }
  if (i < NN) scanbuf[i] = sd[t];
  if (t == 255) bsum[blockIdx.x] = sd[255];
}

__global__ void scan2(const int* __restrict__ bsum, int* __restrict__ boff, int nb) {
  __shared__ int sd[256];
  int t = threadIdx.x;
  int v = (t < nb) ? bsum[t] : 0;
  sd[t] = v;
  __syncthreads();
#pragma unroll
  for (int off = 1; off < 256; off <<= 1) {
    int x = (t >= off) ? sd[t - off] : 0;
    __syncthreads();
    sd[t] += x;
    __syncthreads();
  }
  if (t < nb) boff[t] = sd[t] - v;  // exclusive
}

__global__ void scan3(const int* __restrict__ scanbuf, const int* __restrict__ boff,
                      int* __restrict__ rowptr) {
  int i = blockIdx.x * 256 + threadIdx.x;
  if (i < NN) rowptr[i + 1] = scanbuf[i] + boff[blockIdx.x];
  if (i == 0) rowptr[0] = 0;
}

// ---------------- aggregation: 32 lanes/dst, masked 4-edge unroll, no-max softmax ----
__global__ __launch_bounds__(256) void agg_kernel(
    const unsigned short* __restrict__ htb, const float* __restrict__ a_s,
    const float* __restrict__ a_d, const int* __restrict__ rowptr,
    const int2* __restrict__ ce, const float* __restrict__ bias,
    unsigned short* __restrict__ outb,
    const float* __restrict__ Wn, const float* __restrict__ bn,
    float* __restrict__ outn) {
  int d = blockIdx.x * 8 + (threadIdx.x >> 5);
  if (d >= NN) return;
  int l = threadIdx.x & 31;
  int hh = l >> 2;
  float adh = a_d[d * 8 + hh];
  int r0 = rowptr[d], r1 = rowptr[d + 1];
  float denom = 0.f;
  float4 acc0 = {0.f, 0.f, 0.f, 0.f};
  float4 acc1 = {0.f, 0.f, 0.f, 0.f};
  for (int r = r0; r < r1; r += 4) {
    int s[4];
    float as_[4];
    uint4 q[4];
    bool ok[4];
#pragma unroll
    for (int j = 0; j < 4; ++j) {
      int rj = r + j;
      ok[j] = rj < r1;
      rj = ok[j] ? rj : r1 - 1;  // clamp: duplicate load, weight zeroed
      s[j] = ce[rj].x;
    }
#pragma unroll
    for (int j = 0; j < 4; ++j) {
      as_[j] = a_s[s[j] * 8 + hh];
      q[j] = ((const uint4*)(htb + (size_t)s[j] * HC))[l];
    }
#pragma unroll
    for (int j = 0; j < 4; ++j) {
      float e = as_[j] + adh;
      e = e > 0.f ? e : NEG_SLOPE * e;
      float w = ok[j] ? __expf(e) : 0.f;
      denom += w;
      acc0.x += w * bflo(q[j].x);
      acc0.y += w * bfhi(q[j].x);
      acc0.z += w * bflo(q[j].y);
      acc0.w += w * bfhi(q[j].y);
      acc1.x += w * bflo(q[j].z);
      acc1.y += w * bfhi(q[j].z);
      acc1.z += w * bflo(q[j].w);
      acc1.w += w * bfhi(q[j].w);
    }
  }
  float dv = 1.f / denom;  // denom >= 1 (self-loop)
  float4 b0 = *(const float4*)(bias + l * 8);
  float4 b1 = *(const float4*)(bias + l * 8 + 4);
  float4 o0, o1;
  o0.x = fmaxf(fmaf(acc0.x, dv, b0.x), 0.f);
  o0.y = fmaxf(fmaf(acc0.y, dv, b0.y), 0.f);
  o0.z = fmaxf(fmaf(acc0.z, dv, b0.z), 0.f);
  o0.w = fmaxf(fmaf(acc0.w, dv, b0.w), 0.f);
  o1.x = fmaxf(fmaf(acc1.x, dv, b1.x), 0.f);
  o1.y = fmaxf(fmaf(acc1.y, dv, b1.y), 0.f);
  o1.z = fmaxf(fmaf(acc1.z, dv, b1.z), 0.f);
  o1.w = fmaxf(fmaf(acc1.w, dv, b1.w), 0.f);
  uint4 pb;
  pb.x = (unsigned)f2bf(o0.x) | ((unsigned)f2bf(o0.y) << 16);
  pb.y = (unsigned)f2bf(o0.z) | ((unsigned)f2bf(o0.w) << 16);
  pb.z = (unsigned)f2bf(o1.x) | ((unsigned)f2bf(o1.y) << 16);
  pb.w = (unsigned)f2bf(o1.z) | ((unsigned)f2bf(o1.w) << 16);
  ((uint4*)(outb + (size_t)d * HC))[l] = pb;
  if (outn) {
    const float4* wnp = (const float4*)(Wn + l * 8);
    float4 w0 = wnp[0], w1 = wnp[1];
    float p = o0.x * w0.x + o0.y * w0.y + o0.z * w0.z + o0.w * w0.w +
              o1.x * w1.x + o1.y * w1.y + o1.z * w1.z + o1.w * w1.w;
#pragma unroll
    for (int off = 1; off <= 16; off <<= 1) p += __shfl_xor(p, off);
    if (l == 0) outn[d] = p + bn[0];
  }
}

// ---------------- edge predictions: 16-lane group per edge, 2-edge unroll ----------------
__global__ __launch_bounds__(256) void edge_pred_kernel(
    const unsigned short* __restrict__ h2b, const int* __restrict__ rowptr,
    const int2* __restrict__ ce, const float* __restrict__ We,
    const float* __restrict__ be, float* __restrict__ out) {
  int d = blockIdx.x * 4 + (threadIdx.x >> 6);
  if (d >= NN) return;
  int lane = threadIdx.x & 63;
  int g = lane >> 4, l = lane & 15;
  float b = be[0];

  const uint4* rowd = (const uint4*)(h2b + (size_t)d * HC + l * 16);
  uint4 qd0 = rowd[0], qd1 = rowd[1];
  float wd[16];
  {
    const float4* wep = (const float4*)(We + l * 16);
    float4 w0 = wep[0], w1 = wep[1], w2 = wep[2], w3 = wep[3];
    wd[0] = bflo(qd0.x) * w0.x;  wd[1] = bfhi(qd0.x) * w0.y;
    wd[2] = bflo(qd0.y) * w0.z;  wd[3] = bfhi(qd0.y) * w0.w;
    wd[4] = bflo(qd0.z) * w1.x;  wd[5] = bfhi(qd0.z) * w1.y;
    wd[6] = bflo(qd0.w) * w1.z;  wd[7] = bfhi(qd0.w) * w1.w;
    wd[8] = bflo(qd1.x) * w2.x;  wd[9] = bfhi(qd1.x) * w2.y;
    wd[10] = bflo(qd1.y) * w2.z; wd[11] = bfhi(qd1.y) * w2.w;
    wd[12] = bflo(qd1.z) * w3.x; wd[13] = bfhi(qd1.z) * w3.y;
    wd[14] = bflo(qd1.w) * w3.z; wd[15] = bfhi(qd1.w) * w3.w;
  }

  int r0 = rowptr[d], r1 = rowptr[d + 1];
  for (int r = r0; r < r1; r += 8) {
    int rr0 = r + g, rr1 = r + 4 + g;
    int s0 = 0, id0 = -1, s1 = 0, id1 = -1;
    if (rr0 < r1) { int2 p = ce[rr0]; s0 = p.x; id0 = p.y; }
    if (rr1 < r1) { int2 p = ce[rr1]; s1 = p.x; id1 = p.y; }
    const uint4* ra = (const uint4*)(h2b + (size_t)s0 * HC + l * 16);
    const uint4* rb = (const uint4*)(h2b + (size_t)s1 * HC + l * 16);
    uint4 a0 = ra[0], a1 = ra[1];
    uint4 c0 = rb[0], c1 = rb[1];
    float p0 = bflo(a0.x) * wd[0] + bfhi(a0.x) * wd[1] + bflo(a0.y) * wd[2] +
               bfhi(a0.y) * wd[3] + bflo(a0.z) * wd[4] + bfhi(a0.z) * wd[5] +
               bflo(a0.w) * wd[6] + bfhi(a0.w) * wd[7] + bflo(a1.x) * wd[8] +
               bfhi(a1.x) * wd[9] + bflo(a1.y) * wd[10] + bfhi(a1.y) * wd[11] +
               bflo(a1.z) * wd[12] + bfhi(a1.z) * wd[13] + bflo(a1.w) * wd[14] +
               bfhi(a1.w) * wd[15];
    float p1 = bflo(c0.x) * wd[0] + bfhi(c0.x) * wd[1] + bflo(c0.y) * wd[2] +
               bfhi(c0.y) * wd[3] + bflo(c0.z) * wd[4] + bfhi(c0.z) * wd[5] +
               bflo(c0.w) * wd[6] + bfhi(c0.w) * wd[7] + bflo(c1.x) * wd[8] +
               bfhi(c1.x) * wd[9] + bflo(c1.y) * wd[10] + bfhi(c1.y) * wd[11] +
               bflo(c1.z) * wd[12] + bfhi(c1.z) * wd[13] + bflo(c1.w) * wd[14] +
               bfhi(c1.w) * wd[15];
#pragma unroll
    for (int off = 1; off <= 8; off <<= 1) {
      p0 += __shfl_xor(p0, off);
      p1 += __shfl_xor(p1, off);
    }
    if (l == 0) {
      if (id0 >= 0) out[id0] = p0 + b;
      if (id1 >= 0) out[id1] = p1 + b;
    }
  }
}

extern "C" void kernel_launch(void* const* d_in, const int* in_sizes, int n_in,
                              void* d_out, int out_size, void* d_ws, size_t ws_size,
                              hipStream_t stream) {
  const float* x  = (const float*)d_in[0];
  const int* ei   = (const int*)d_in[1];
  const float* W1 = (const float*)d_in[3];
  const float* as1 = (const float*)d_in[4];
  const float* ad1 = (const float*)d_in[5];
  const float* b1 = (const float*)d_in[6];
  const float* W2 = (const float*)d_in[7];
  const float* as2 = (const float*)d_in[8];
  const float* ad2 = (const float*)d_in[9];
  const float* b2 = (const float*)d_in[10];
  const float* We = (const float*)d_in[11];
  const float* be = (const float*)d_in[12];
  const float* Wn = (const float*)d_in[13];
  const float* bn = (const float*)d_in[14];
  float* out = (float*)d_out;

  char* wsp = (char*)d_ws;
  auto alloc = [&](size_t bytes) {
    char* p = wsp;
    wsp += (bytes + 255) & ~(size_t)255;
    return p;
  };
  unsigned short* hbA = (unsigned short*)alloc((size_t)NN * HC * 2); // gemm out (both layers)
  unsigned short* h1b = (unsigned short*)alloc((size_t)NN * HC * 2); // agg1 out (xh aliases)
  unsigned short* hbB = (unsigned short*)alloc((size_t)NN * HC * 2); // agg2 out
  float* a_s = (float*)alloc((size_t)NN * 8 * 4);
  float* a_d = (float*)alloc((size_t)NN * 8 * 4);
  int* rowptr = (int*)alloc((size_t)(NN + 1) * 4);
  int2* ce = (int2*)alloc((size_t)(NE + NN + 8) * 8);  // (src, edge-id) pairs
  int* counts = (int*)alloc((size_t)NN * 4);
  int* tmp = (int*)alloc((size_t)NN * 4);
  int* scanbuf = (int*)alloc((size_t)NN * 4);
  int* bsum = (int*)alloc(256 * 4);
  int* boff = (int*)alloc(256 * 4);
  unsigned short* W1th = (unsigned short*)alloc((size_t)FIN * HC * 2);
  unsigned short* W1tl = (unsigned short*)alloc((size_t)FIN * HC * 2);
  unsigned short* W2th = (unsigned short*)alloc((size_t)HC * HC * 2);
  unsigned short* W2tl = (unsigned short*)alloc((size_t)HC * HC * 2);

  unsigned short* xh = h1b;  // x bf16 consumed by gemm1 before agg1 writes h1b

  const int NB = (NN + 255) / 256;

  // prep: zero counters + all dtype conversions (one launch)
  prep_kernel<<<NB_ZERO + NB_X + NB_W1 + NB_W2, 256, 0, stream>>>(
      x, xh, W1, W1th, W1tl, W2, W2th, W2tl, counts, tmp);
  // CSR build
  hist_kernel<<<(NE + 255) / 256, 256, 0, stream>>>(ei, counts);
  scan1<<<NB, 256, 0, stream>>>(counts, scanbuf, bsum);
  scan2<<<1, 256, 0, stream>>>(bsum, boff, NB);
  scan3<<<NB, 256, 0, stream>>>(scanbuf, boff, rowptr);

  // layer 1 gemm+coef, with CSR scatter fused into LEADING blocks
  gemm_coef<<<NSB + GEMM_BLOCKS, 256, 0, stream>>>(
      xh, W1th, W1tl, as1, ad1, hbA, a_s, a_d, NN, FIN, ei, rowptr, tmp, ce, NSB);
  agg_kernel<<<NN / 8, 256, 0, stream>>>(hbA, a_s, a_d, rowptr, ce, b1, h1b,
                                         (const float*)nullptr, (const float*)nullptr,
                                         (float*)nullptr);

  // layer 2 (node_pred fused into agg epilogue)
  gemm_coef<<<GEMM_BLOCKS, 256, 0, stream>>>(
      h1b, W2th, W2tl, as2, ad2, hbA, a_s, a_d, NN, HC,
      (const int*)nullptr, rowptr, tmp, ce, 0);
  agg_kernel<<<NN / 8, 256, 0, stream>>>(hbA, a_s, a_d, rowptr, ce, b2, hbB,
                                         Wn, bn, out + NE);

  // edge predictions
  edge_pred_kernel<<<NN / 4, 256, 0, stream>>>(hbB, rowptr, ce, We, be, out);
}

// Round 14
// 438.134 us; speedup vs baseline: 1.0164x; 1.0164x over previous
//
#include <hip/hip_runtime.h>
#include <hip/hip_bf16.h>

#define NN 50000
#define NE 800000
#define FIN 128
#define HC 256
#define NEG_SLOPE 0.2f

#define GEMM_BLOCKS 1564  // ceil(NN/64)*2  (64x128 tiles)
#define NSB 3321          // ceil((NE+NN)/256) scatter blocks
#define NB_ZERO 196       // ceil(NN/256)
#define NB_X 6250         // NN*FIN/4/256
#define NB_W1 128         // FIN*HC/256
#define NB_W2 256         // HC*HC/256

typedef short bf16x8 __attribute__((ext_vector_type(8)));
typedef float f32x4 __attribute__((ext_vector_type(4)));

__device__ __forceinline__ unsigned short f2bf(float f) {
  unsigned u = __float_as_uint(f);
  u += 0x7fff + ((u >> 16) & 1);  // RTN-even
  return (unsigned short)(u >> 16);
}
__device__ __forceinline__ float bf2f(unsigned short s) {
  return __uint_as_float((unsigned)s << 16);
}
__device__ __forceinline__ float bflo(unsigned u) { return __uint_as_float(u << 16); }
__device__ __forceinline__ float bfhi(unsigned u) { return __uint_as_float(u & 0xffff0000u); }

// ---------------- fused prep: zero counts/tmp + convert x + transpose W1,W2 ----
__global__ __launch_bounds__(256) void prep_kernel(
    const float* __restrict__ X, unsigned short* __restrict__ Xh,
    const float* __restrict__ W1, unsigned short* __restrict__ W1th,
    const float* __restrict__ W2, unsigned short* __restrict__ W2th,
    int* __restrict__ counts, int* __restrict__ tmp) {
  int b = blockIdx.x, t = threadIdx.x;
  if (b < NB_ZERO) {
    int i = b * 256 + t;
    if (i < NN) { counts[i] = 0; tmp[i] = 0; }
  } else if (b < NB_ZERO + NB_X) {
    int i = (b - NB_ZERO) * 256 + t;  // exact: NN*FIN/4 = 1.6M
    float4 v = ((const float4*)X)[i];
    ushort4 h;
    h.x = f2bf(v.x); h.y = f2bf(v.y); h.z = f2bf(v.z); h.w = f2bf(v.w);
    ((ushort4*)Xh)[i] = h;
  } else if (b < NB_ZERO + NB_X + NB_W1) {
    int j = (b - NB_ZERO - NB_X) * 256 + t;  // j = n*K+k, output-contiguous, K=128
    int n = j >> 7, k = j & 127;
    W1th[j] = f2bf(W1[k * HC + n]);
  } else {
    int j = (b - NB_ZERO - NB_X - NB_W1) * 256 + t;  // K=256
    int n = j >> 8, k = j & 255;
    W2th[j] = f2bf(W2[k * HC + n]);
  }
}

// ---------------- MFMA GEMM + fused coef, 64x128 tile (r12-proven loop shape) -------
// Cb(bf16) = A_bf16 @ B_bf16^T(stored [N][K]); SINGLE-term bf16 (W residual dropped:
// adds ~sqrt(K)*|W|*2^-9 ~ 2e-3 noise, same order as existing h bf16 rounding).
// NO register prefetch (r13: compiler sank the prefetch loads, VGPR 56, +12us — revert).
// Coef: 16-lane shuffle reduce -> LDS -> one float4/row (contiguous; scattered 4B
// coef stores amplified WRITE to 85MB in r11). C stored as quad-contiguous 2B
// scalars (r10's strided uint4 stores amplified writes 3x — do not repeat).
// Scatter blocks FIRST in the layer-1 grid so they complete under the gemm.
__global__ __launch_bounds__(256) void gemm_coef(
    const unsigned short* __restrict__ A, const unsigned short* __restrict__ Bth,
    const float* __restrict__ att_s, const float* __restrict__ att_d,
    unsigned short* __restrict__ Cb, float* __restrict__ a_s,
    float* __restrict__ a_d, int M, int K,
    const int* __restrict__ ei, const int* __restrict__ rowptr,
    int* __restrict__ tmpc, int2* __restrict__ ce, int scat) {
  __shared__ unsigned short sA[64 * 40];    // stride 40 shorts: <=2-way banks (free)
  __shared__ unsigned short sB[128 * 40];
  __shared__ float sCS[64][4];
  __shared__ float sCD[64][4];

  int bid = blockIdx.x, t = threadIdx.x;
  if (bid < scat) {
    // fused scatter path (layer-1 launch only), dispatched before gemm blocks
    int e = bid * 256 + t;
    if (e < NE + NN) {
      int s, d, id;
      if (e < NE) { s = ei[e]; d = ei[NE + e]; id = e; }
      else { s = d = e - NE; id = -1; }
      int pos = rowptr[d] + atomicAdd(&tmpc[d], 1);
      ce[pos] = make_int2(s, id);
    }
    return;
  }
  int gid = bid - scat;

  int w = t >> 6, lane = t & 63;
  int quad = lane >> 4, lrow = lane & 15;
  int m0 = (gid >> 1) * 64, n0 = (gid & 1) * 128;
  int rm = (w & 1) * 32, cn = (w >> 1) * 64;

  f32x4 acc[2][4] = {};

  for (int k0 = 0; k0 < K; k0 += 32) {
    // stage A: 64 rows x 4 chunks = 256 -> 1/thread
    {
      int row = t >> 2, q = t & 3;
      int gm = m0 + row;
      if (gm >= M) gm = M - 1;
      *(uint4*)(sA + row * 40 + q * 8) = *(const uint4*)(A + (size_t)gm * K + k0 + q * 8);
    }
    // stage B: 128 rows x 4 chunks = 512 -> 2/thread
#pragma unroll
    for (int i = 0; i < 2; ++i) {
      int idx = t + i * 256;
      int row = idx >> 2, q = idx & 3;
      *(uint4*)(sB + row * 40 + q * 8) =
          *(const uint4*)(Bth + (size_t)(n0 + row) * K + k0 + q * 8);
    }
    __syncthreads();

    bf16x8 fa[2];
#pragma unroll
    for (int mi = 0; mi < 2; ++mi)
      fa[mi] = *(const bf16x8*)(sA + (rm + mi * 16 + lrow) * 40 + quad * 8);
#pragma unroll
    for (int ni = 0; ni < 4; ++ni) {
      bf16x8 fb = *(const bf16x8*)(sB + (cn + ni * 16 + lrow) * 40 + quad * 8);
#pragma unroll
      for (int mi = 0; mi < 2; ++mi)
        acc[mi][ni] = __builtin_amdgcn_mfma_f32_16x16x32_bf16(fa[mi], fb, acc[mi][ni], 0, 0, 0);
    }
    __syncthreads();
  }

  // att values for this lane's 4 columns (hoisted)
  float vs[4], vd[4];
#pragma unroll
  for (int ni = 0; ni < 4; ++ni) {
    int gn = n0 + cn + ni * 16 + lrow;
    vs[ni] = att_s[gn];
    vd[ni] = att_d[gn];
  }
  int h4e = cn >> 5;  // local head pair base: 0 (cols 0-63) or 2 (cols 64-127)

  // C/D layout: col = lane&15, row = quad*4 + reg  [m89-verified]
#pragma unroll
  for (int mi = 0; mi < 2; ++mi) {
#pragma unroll
    for (int r = 0; r < 4; ++r) {
      int lr = rm + mi * 16 + quad * 4 + r;  // local row 0..63
      int gm = m0 + lr;
      if (gm < M) {
#pragma unroll
        for (int ni = 0; ni < 4; ++ni) {
          int gn = n0 + cn + ni * 16 + lrow;
          Cb[(size_t)gm * HC + gn] = f2bf(acc[mi][ni][r]);
        }
      }
      // per-head partial dots: ni 0,1 -> local head h4e ; ni 2,3 -> h4e+1
      float pse = acc[mi][0][r] * vs[0] + acc[mi][1][r] * vs[1];
      float pso = acc[mi][2][r] * vs[2] + acc[mi][3][r] * vs[3];
      float pde = acc[mi][0][r] * vd[0] + acc[mi][1][r] * vd[1];
      float pdo = acc[mi][2][r] * vd[2] + acc[mi][3][r] * vd[3];
#pragma unroll
      for (int off = 1; off <= 8; off <<= 1) {
        pse += __shfl_xor(pse, off);
        pso += __shfl_xor(pso, off);
        pde += __shfl_xor(pde, off);
        pdo += __shfl_xor(pdo, off);
      }
      if (lrow == 0) {
        sCS[lr][h4e] = pse;
        sCS[lr][h4e + 1] = pso;
        sCD[lr][h4e] = pde;
        sCD[lr][h4e + 1] = pdo;
      }
    }
  }
  __syncthreads();
  // contiguous 16B coef writeback (one float4 per row per array)
  if (t < 64) {
    int gm = m0 + t;
    if (gm < M) {
      int o = (n0 >> 5);  // 0 or 4
      *(float4*)(a_s + (size_t)gm * 8 + o) = *(const float4*)&sCS[t][0];
      *(float4*)(a_d + (size_t)gm * 8 + o) = *(const float4*)&sCD[t][0];
    }
  }
}

// ---------------- CSR build ----------------
__global__ void hist_kernel(const int* __restrict__ ei, int* __restrict__ counts) {
  int e = blockIdx.x * 256 + threadIdx.x;
  if (e < NE) atomicAdd(&counts[ei[NE + e]], 1);
}

__global__ void scan1(const int* __restrict__ counts, int* __restrict__ scanbuf,
                      int* __restrict__ bsum) {
  __shared__ int sd[256];
  int t = threadIdx.x;
  int i = blockIdx.x * 256 + t;
  int v = (i < NN) ? counts[i] + 1 : 0;  // +1 = self-loop
  sd[t] = v;
  __syncthreads();
#pragma unroll
  for (int off = 1; off < 256; off <<= 1) {
    int x = (t >= off) ? sd[t - off] : 0;
    __syncthreads();
    sd[t] += x;
    __syncthreads();
  }
  if (i < NN) scanbuf[i] = sd[t];
  if (t == 255) bsum[blockIdx.x] = sd[255];
}

__global__ void scan2(const int* __restrict__ bsum, int* __restrict__ boff, int nb) {
  __shared__ int sd[256];
  int t = threadIdx.x;
  int v = (t < nb) ? bsum[t] : 0;
  sd[t] = v;
  __syncthreads();
#pragma unroll
  for (int off = 1; off < 256; off <<= 1) {
    int x = (t >= off) ? sd[t - off] : 0;
    __syncthreads();
    sd[t] += x;
    __syncthreads();
  }
  if (t < nb) boff[t] = sd[t] - v;  // exclusive
}

__global__ void scan3(const int* __restrict__ scanbuf, const int* __restrict__ boff,
                      int* __restrict__ rowptr) {
  int i = blockIdx.x * 256 + threadIdx.x;
  if (i < NN) rowptr[i + 1] = scanbuf[i] + boff[blockIdx.x];
  if (i == 0) rowptr[0] = 0;
}

// ---------------- aggregation: 32 lanes/dst, masked 4-edge unroll, no-max softmax ----
__global__ __launch_bounds__(256) void agg_kernel(
    const unsigned short* __restrict__ htb, const float* __restrict__ a_s,
    const float* __restrict__ a_d, const int* __restrict__ rowptr,
    const int2* __restrict__ ce, const float* __restrict__ bias,
    unsigned short* __restrict__ outb,
    const float* __restrict__ Wn, const float* __restrict__ bn,
    float* __restrict__ outn) {
  int d = blockIdx.x * 8 + (threadIdx.x >> 5);
  if (d >= NN) return;
  int l = threadIdx.x & 31;
  int hh = l >> 2;
  float adh = a_d[d * 8 + hh];
  int r0 = rowptr[d], r1 = rowptr[d + 1];
  float denom = 0.f;
  float4 acc0 = {0.f, 0.f, 0.f, 0.f};
  float4 acc1 = {0.f, 0.f, 0.f, 0.f};
  for (int r = r0; r < r1; r += 4) {
    int s[4];
    float as_[4];
    uint4 q[4];
    bool ok[4];
#pragma unroll
    for (int j = 0; j < 4; ++j) {
      int rj = r + j;
      ok[j] = rj < r1;
      rj = ok[j] ? rj : r1 - 1;  // clamp: duplicate load, weight zeroed
      s[j] = ce[rj].x;
    }
#pragma unroll
    for (int j = 0; j < 4; ++j) {
      as_[j] = a_s[s[j] * 8 + hh];
      q[j] = ((const uint4*)(htb + (size_t)s[j] * HC))[l];
    }
#pragma unroll
    for (int j = 0; j < 4; ++j) {
      float e = as_[j] + adh;
      e = e > 0.f ? e : NEG_SLOPE * e;
      float w = ok[j] ? __expf(e) : 0.f;
      denom += w;
      acc0.x += w * bflo(q[j].x);
      acc0.y += w * bfhi(q[j].x);
      acc0.z += w * bflo(q[j].y);
      acc0.w += w * bfhi(q[j].y);
      acc1.x += w * bflo(q[j].z);
      acc1.y += w * bfhi(q[j].z);
      acc1.z += w * bflo(q[j].w);
      acc1.w += w * bfhi(q[j].w);
    }
  }
  float dv = 1.f / denom;  // denom >= 1 (self-loop)
  float4 b0 = *(const float4*)(bias + l * 8);
  float4 b1 = *(const float4*)(bias + l * 8 + 4);
  float4 o0, o1;
  o0.x = fmaxf(fmaf(acc0.x, dv, b0.x), 0.f);
  o0.y = fmaxf(fmaf(acc0.y, dv, b0.y), 0.f);
  o0.z = fmaxf(fmaf(acc0.z, dv, b0.z), 0.f);
  o0.w = fmaxf(fmaf(acc0.w, dv, b0.w), 0.f);
  o1.x = fmaxf(fmaf(acc1.x, dv, b1.x), 0.f);
  o1.y = fmaxf(fmaf(acc1.y, dv, b1.y), 0.f);
  o1.z = fmaxf(fmaf(acc1.z, dv, b1.z), 0.f);
  o1.w = fmaxf(fmaf(acc1.w, dv, b1.w), 0.f);
  uint4 pb;
  pb.x = (unsigned)f2bf(o0.x) | ((unsigned)f2bf(o0.y) << 16);
  pb.y = (unsigned)f2bf(o0.z) | ((unsigned)f2bf(o0.w) << 16);
  pb.z = (unsigned)f2bf(o1.x) | ((unsigned)f2bf(o1.y) << 16);
  pb.w = (unsigned)f2bf(o1.z) | ((unsigned)f2bf(o1.w) << 16);
  ((uint4*)(outb + (size_t)d * HC))[l] = pb;
  if (outn) {
    const float4* wnp = (const float4*)(Wn + l * 8);
    float4 w0 = wnp[0], w1 = wnp[1];
    float p = o0.x * w0.x + o0.y * w0.y + o0.z * w0.z + o0.w * w0.w +
              o1.x * w1.x + o1.y * w1.y + o1.z * w1.z + o1.w * w1.w;
#pragma unroll
    for (int off = 1; off <= 16; off <<= 1) p += __shfl_xor(p, off);
    if (l == 0) outn[d] = p + bn[0];
  }
}

// ---------------- edge predictions: 16-lane group per edge, 2-edge unroll ----------------
__global__ __launch_bounds__(256) void edge_pred_kernel(
    const unsigned short* __restrict__ h2b, const int* __restrict__ rowptr,
    const int2* __restrict__ ce, const float* __restrict__ We,
    const float* __restrict__ be, float* __restrict__ out) {
  int d = blockIdx.x * 4 + (threadIdx.x >> 6);
  if (d >= NN) return;
  int lane = threadIdx.x & 63;
  int g = lane >> 4, l = lane & 15;
  float b = be[0];

  const uint4* rowd = (const uint4*)(h2b + (size_t)d * HC + l * 16);
  uint4 qd0 = rowd[0], qd1 = rowd[1];
  float wd[16];
  {
    const float4* wep = (const float4*)(We + l * 16);
    float4 w0 = wep[0], w1 = wep[1], w2 = wep[2], w3 = wep[3];
    wd[0] = bflo(qd0.x) * w0.x;  wd[1] = bfhi(qd0.x) * w0.y;
    wd[2] = bflo(qd0.y) * w0.z;  wd[3] = bfhi(qd0.y) * w0.w;
    wd[4] = bflo(qd0.z) * w1.x;  wd[5] = bfhi(qd0.z) * w1.y;
    wd[6] = bflo(qd0.w) * w1.z;  wd[7] = bfhi(qd0.w) * w1.w;
    wd[8] = bflo(qd1.x) * w2.x;  wd[9] = bfhi(qd1.x) * w2.y;
    wd[10] = bflo(qd1.y) * w2.z; wd[11] = bfhi(qd1.y) * w2.w;
    wd[12] = bflo(qd1.z) * w3.x; wd[13] = bfhi(qd1.z) * w3.y;
    wd[14] = bflo(qd1.w) * w3.z; wd[15] = bfhi(qd1.w) * w3.w;
  }

  int r0 = rowptr[d], r1 = rowptr[d + 1];
  for (int r = r0; r < r1; r += 8) {
    int rr0 = r + g, rr1 = r + 4 + g;
    int s0 = 0, id0 = -1, s1 = 0, id1 = -1;
    if (rr0 < r1) { int2 p = ce[rr0]; s0 = p.x; id0 = p.y; }
    if (rr1 < r1) { int2 p = ce[rr1]; s1 = p.x; id1 = p.y; }
    const uint4* ra = (const uint4*)(h2b + (size_t)s0 * HC + l * 16);
    const uint4* rb = (const uint4*)(h2b + (size_t)s1 * HC + l * 16);
    uint4 a0 = ra[0], a1 = ra[1];
    uint4 c0 = rb[0], c1 = rb[1];
    float p0 = bflo(a0.x) * wd[0] + bfhi(a0.x) * wd[1] + bflo(a0.y) * wd[2] +
               bfhi(a0.y) * wd[3] + bflo(a0.z) * wd[4] + bfhi(a0.z) * wd[5] +
               bflo(a0.w) * wd[6] + bfhi(a0.w) * wd[7] + bflo(a1.x) * wd[8] +
               bfhi(a1.x) * wd[9] + bflo(a1.y) * wd[10] + bfhi(a1.y) * wd[11] +
               bflo(a1.z) * wd[12] + bfhi(a1.z) * wd[13] + bflo(a1.w) * wd[14] +
               bfhi(a1.w) * wd[15];
    float p1 = bflo(c0.x) * wd[0] + bfhi(c0.x) * wd[1] + bflo(c0.y) * wd[2] +
               bfhi(c0.y) * wd[3] + bflo(c0.z) * wd[4] + bfhi(c0.z) * wd[5] +
               bflo(c0.w) * wd[6] + bfhi(c0.w) * wd[7] + bflo(c1.x) * wd[8] +
               bfhi(c1.x) * wd[9] + bflo(c1.y) * wd[10] + bfhi(c1.y) * wd[11] +
               bflo(c1.z) * wd[12] + bfhi(c1.z) * wd[13] + bflo(c1.w) * wd[14] +
               bfhi(c1.w) * wd[15];
#pragma unroll
    for (int off = 1; off <= 8; off <<= 1) {
      p0 += __shfl_xor(p0, off);
      p1 += __shfl_xor(p1, off);
    }
    if (l == 0) {
      if (id0 >= 0) out[id0] = p0 + b;
      if (id1 >= 0) out[id1] = p1 + b;
    }
  }
}

extern "C" void kernel_launch(void* const* d_in, const int* in_sizes, int n_in,
                              void* d_out, int out_size, void* d_ws, size_t ws_size,
                              hipStream_t stream) {
  const float* x  = (const float*)d_in[0];
  const int* ei   = (const int*)d_in[1];
  const float* W1 = (const float*)d_in[3];
  const float* as1 = (const float*)d_in[4];
  const float* ad1 = (const float*)d_in[5];
  const float* b1 = (const float*)d_in[6];
  const float* W2 = (const float*)d_in[7];
  const float* as2 = (const float*)d_in[8];
  const float* ad2 = (const float*)d_in[9];
  const float* b2 = (const float*)d_in[10];
  const float* We = (const float*)d_in[11];
  const float* be = (const float*)d_in[12];
  const float* Wn = (const float*)d_in[13];
  const float* bn = (const float*)d_in[14];
  float* out = (float*)d_out;

  char* wsp = (char*)d_ws;
  auto alloc = [&](size_t bytes) {
    char* p = wsp;
    wsp += (bytes + 255) & ~(size_t)255;
    return p;
  };
  unsigned short* hbA = (unsigned short*)alloc((size_t)NN * HC * 2); // gemm out (both layers)
  unsigned short* h1b = (unsigned short*)alloc((size_t)NN * HC * 2); // agg1 out (xh aliases)
  unsigned short* hbB = (unsigned short*)alloc((size_t)NN * HC * 2); // agg2 out
  float* a_s = (float*)alloc((size_t)NN * 8 * 4);
  float* a_d = (float*)alloc((size_t)NN * 8 * 4);
  int* rowptr = (int*)alloc((size_t)(NN + 1) * 4);
  int2* ce = (int2*)alloc((size_t)(NE + NN + 8) * 8);  // (src, edge-id) pairs
  int* counts = (int*)alloc((size_t)NN * 4);
  int* tmp = (int*)alloc((size_t)NN * 4);
  int* scanbuf = (int*)alloc((size_t)NN * 4);
  int* bsum = (int*)alloc(256 * 4);
  int* boff = (int*)alloc(256 * 4);
  unsigned short* W1th = (unsigned short*)alloc((size_t)FIN * HC * 2);
  unsigned short* W2th = (unsigned short*)alloc((size_t)HC * HC * 2);

  unsigned short* xh = h1b;  // x bf16 consumed by gemm1 before agg1 writes h1b

  const int NB = (NN + 255) / 256;

  // prep: zero counters + all dtype conversions (one launch)
  prep_kernel<<<NB_ZERO + NB_X + NB_W1 + NB_W2, 256, 0, stream>>>(
      x, xh, W1, W1th, W2, W2th, counts, tmp);
  // CSR build
  hist_kernel<<<(NE + 255) / 256, 256, 0, stream>>>(ei, counts);
  scan1<<<NB, 256, 0, stream>>>(counts, scanbuf, bsum);
  scan2<<<1, 256, 0, stream>>>(bsum, boff, NB);
  scan3<<<NB, 256, 0, stream>>>(scanbuf, boff, rowptr);

  // layer 1 gemm+coef, with CSR scatter fused into LEADING blocks
  gemm_coef<<<NSB + GEMM_BLOCKS, 256, 0, stream>>>(
      xh, W1th, as1, ad1, hbA, a_s, a_d, NN, FIN, ei, rowptr, tmp, ce, NSB);
  agg_kernel<<<NN / 8, 256, 0, stream>>>(hbA, a_s, a_d, rowptr, ce, b1, h1b,
                                         (const float*)nullptr, (const float*)nullptr,
                                         (float*)nullptr);

  // layer 2 (node_pred fused into agg epilogue)
  gemm_coef<<<GEMM_BLOCKS, 256, 0, stream>>>(
      h1b, W2th, as2, ad2, hbA, a_s, a_d, NN, HC,
      (const int*)nullptr, rowptr, tmp, ce, 0);
  agg_kernel<<<NN / 8, 256, 0, stream>>>(hbA, a_s, a_d, rowptr, ce, b2, hbB,
                                         Wn, bn, out + NE);

  // edge predictions
  edge_pred_kernel<<<NN / 4, 256, 0, stream>>>(hbB, rowptr, ce, We, be, out);
}